// Round 5
// baseline (349.983 us; speedup 1.0000x reference)
//
#include <hip/hip_runtime.h>
#include <hip/hip_bf16.h>
#include <cstdint>
#include <cstddef>

#define NTOK 8192
#define DH   2048
#define DF   1376
#define DFP  1408      // h row stride (K-padded for down-GEMM BK=64)
#define NE   8
#define CAP  1280

typedef __bf16 bf16x8 __attribute__((ext_vector_type(8)));
typedef float  f32x4  __attribute__((ext_vector_type(4)));

#define BARRIER() asm volatile("s_barrier" ::: "memory")
#define WAITV0()  asm volatile("s_waitcnt vmcnt(0)" ::: "memory")
#define WAITV6()  asm volatile("s_waitcnt vmcnt(6)" ::: "memory")
#define WAITV8()  asm volatile("s_waitcnt vmcnt(8)" ::: "memory")
#define SETPRIO(n) __builtin_amdgcn_s_setprio(n)

__device__ __forceinline__ uint32_t pk2(float a, float b) {
  float2 f; f.x = a; f.y = b;
  union { __hip_bfloat162 h; uint32_t u; } cv;
  cv.h = __float22bfloat162_rn(f);
  return cv.u;
}
__device__ __forceinline__ ushort bf16bits(float a) {
  return (ushort)(pk2(a, 0.f) & 0xFFFFu);
}
// async global->LDS, 16B/lane; lds ptr wave-uniform, HW adds lane*16
__device__ __forceinline__ void gload16(const ushort* g, ushort* l) {
  __builtin_amdgcn_global_load_lds(
      (const __attribute__((address_space(1))) uint32_t*)(const void*)g,
      (__attribute__((address_space(3))) uint32_t*)(void*)l,
      16, 0, 0);
}

// ---------------- routing ----------------
__global__ void routing_kernel(const int* __restrict__ idx, int* __restrict__ tok_slot,
                               int* __restrict__ tok_keep) {
  __shared__ int cnt[256][NE];
  const int t = threadIdx.x;
  for (int s = t; s < NE * CAP; s += 256) tok_slot[s] = -1;
  unsigned long long cA = 0ull, cB = 0ull;
  const int per = NTOK / 256, base = t * per;
  for (int i = 0; i < per; ++i) {
    int e = idx[base + i];
    unsigned long long inc = 1ull << ((e & 3) * 16);
    if (e < 4) cA += inc; else cB += inc;
  }
#pragma unroll
  for (int e = 0; e < 4; ++e) cnt[t][e]     = (int)((cA >> (e * 16)) & 0xFFFF);
#pragma unroll
  for (int e = 0; e < 4; ++e) cnt[t][4 + e] = (int)((cB >> (e * 16)) & 0xFFFF);
  __syncthreads();
  if (t < NE) {
    int run = 0;
    for (int i = 0; i < 256; ++i) { int c = cnt[i][t]; cnt[i][t] = run; run += c; }
  }
  __syncthreads();
  cA = 0ull; cB = 0ull;
#pragma unroll
  for (int e = 0; e < 4; ++e) cA |= (unsigned long long)(cnt[t][e] & 0xFFFF) << (e * 16);
#pragma unroll
  for (int e = 0; e < 4; ++e) cB |= (unsigned long long)(cnt[t][4 + e] & 0xFFFF) << (e * 16);
  for (int i = 0; i < per; ++i) {
    int token = base + i;
    int e = idx[token];
    int sh = (e & 3) * 16;
    int r = (int)(((e < 4 ? cA : cB) >> sh) & 0xFFFF);
    unsigned long long inc = 1ull << sh;
    if (e < 4) cA += inc; else cB += inc;
    bool keep = (r < CAP);
    tok_keep[token] = keep ? 1 : 0;
    if (keep) tok_slot[e * CAP + r] = token;
  }
}

// ---------------- y rows for dropped tokens -> 0 ----------------
__global__ void zero_dropped(const int* __restrict__ keep, float* __restrict__ y) {
  if (keep[blockIdx.x]) return;
  float4 z = {0.f, 0.f, 0.f, 0.f};
  float* p = y + (size_t)blockIdx.x * DH + threadIdx.x * 8;
  *(float4*)p = z;
  *(float4*)(p + 4) = z;
}

// ---------------- x f32 -> bf16 ----------------
__global__ void convert_x(const float* __restrict__ x, ushort* __restrict__ xb) {
  int i = (blockIdx.x * 256 + threadIdx.x) * 8;
  float4 a = *(const float4*)(x + i);
  float4 b = *(const float4*)(x + i + 4);
  uint4 p = { pk2(a.x, a.y), pk2(a.z, a.w), pk2(b.x, b.y), pk2(b.z, b.w) };
  *(uint4*)(xb + i) = p;
}

// ---------------- w [E][K][N] f32 -> [E][N][K] bf16 ----------------
__global__ __launch_bounds__(256) void transpose_cvt(
    const float* __restrict__ in, ushort* __restrict__ out, int K, int N) {
  __shared__ ushort T[64][72];
  const int tid = threadIdx.x;
  const int n0 = blockIdx.x * 64, k0 = blockIdx.y * 64;
  const size_t eoff_in  = (size_t)blockIdx.z * K * N;
  const size_t eoff_out = (size_t)blockIdx.z * N * K;
  const int kr = tid >> 4;
  const int nc = (tid & 15) * 4;
#pragma unroll
  for (int it = 0; it < 4; ++it) {
    int k = k0 + kr + it * 16;
    int n = n0 + nc;
    float4 v = {0.f, 0.f, 0.f, 0.f};
    if (k < K && n + 4 <= N) v = *(const float4*)(in + eoff_in + (size_t)k * N + n);
    T[nc + 0][kr + it * 16] = bf16bits(v.x);
    T[nc + 1][kr + it * 16] = bf16bits(v.y);
    T[nc + 2][kr + it * 16] = bf16bits(v.z);
    T[nc + 3][kr + it * 16] = bf16bits(v.w);
  }
  __syncthreads();
  const int nr = tid >> 2;
  const int kc = tid & 3;
#pragma unroll
  for (int it = 0; it < 2; ++it) {
    int kloc = kc * 16 + it * 8;
    int n = n0 + nr, k = k0 + kloc;
    if (n < N && k + 8 <= K)
      *(uint4*)(out + eoff_out + (size_t)n * K + k) = *(const uint4*)&T[nr][kloc];
  }
}

// ---------------- zero h pad cols [DF, DFP) ----------------
__global__ void pad_h(ushort* __restrict__ h) {
  int idx = blockIdx.x * 512 + threadIdx.x;   // 40960 total
  int row = idx >> 2, q = idx & 3;
  uint4 z = {0u, 0u, 0u, 0u};
  *(uint4*)(h + (size_t)row * DFP + DF + q * 8) = z;
}

// ======================================================================
// GEMM1 (256Mx128N, BK=32, QUAD-buffer, 8 waves 4Mx2N of 64x64 dual-B):
//   h = silu(Xe*Wg) .* (Xe*Wu)
// ONE barrier per K-tile: region = {12 ds_read | 4 gload(t+3) | 32 MFMA}
// LDS 128KB: A[4][16KB]@0, Bg[4][8KB]@64K, Bu[4][8KB]@96K
// Rows are 64B (BK=32): swizzle byte ^= ((row&3)<<4) (2-way max = free).
// vmcnt: 4 loads/tile, 3 tiles in flight -> WAITV8; V0 at t>=NT-2.
// ======================================================================
__global__ __launch_bounds__(512, 1) void gemm_gateup3(
    const ushort* __restrict__ xb, const ushort* __restrict__ wgt,
    const ushort* __restrict__ wut, const int* __restrict__ tok_slot,
    ushort* __restrict__ h)
{
  __shared__ __align__(16) char sm[131072];
  const int tid = threadIdx.x, lane = tid & 63, wid = tid >> 6;
  const int wr = wid >> 1, wc = wid & 1;
  const int l15 = lane & 15, l4 = lane >> 4;

  // XCD swizzle: 440 blocks = 8 XCDs x 55 (one expert: 5 mt x 11 nt)
  int wgid = (blockIdx.x & 7) * 55 + (blockIdx.x >> 3);
  const int e = wgid / 55;
  const int rem = wgid - e * 55;
  const int mt = rem / 11, nt = rem - (rem / 11) * 11;
  const int n0 = nt * 128;

  // staging sources (pre-swizzled for 64B rows, loop-invariant)
  const ushort* srcA[2]; const ushort* srcBg; const ushort* srcBu;
#pragma unroll
  for (int c = 0; c < 2; ++c) {
    int o = c * 8192 + wid * 1024 + lane * 16;      // within 16KB A tile
    int os = o ^ (((o >> 6) & 3) << 4);
    int row = os >> 6, kb = os & 63;
    int tk = tok_slot[e * CAP + mt * 256 + row];
    if (tk < 0) tk = 0;                              // finite garbage; discarded
    srcA[c] = xb + (size_t)tk * DH + (kb >> 1);
  }
  {
    int o = wid * 1024 + lane * 16;                  // within 8KB B tile
    int os = o ^ (((o >> 6) & 3) << 4);
    int row = os >> 6, kb = os & 63;
    int n = n0 + row; if (n > DF - 1) n = DF - 1;
    srcBg = wgt + ((size_t)e * DF + n) * DH + (kb >> 1);
    srcBu = wut + ((size_t)e * DF + n) * DH + (kb >> 1);
  }
  // fragment read offsets (row*64B, swizzle ^((row&3)<<4); row&3 == l15&3)
  int aoff[4], boff[4];
#pragma unroll
  for (int i = 0; i < 4; ++i) {
    int row = wr * 64 + i * 16 + l15;
    aoff[i] = row * 64 + ((l4 * 16) ^ ((l15 & 3) << 4));
  }
#pragma unroll
  for (int j = 0; j < 4; ++j) {
    int row = wc * 64 + j * 16 + l15;
    boff[j] = row * 64 + ((l4 * 16) ^ ((l15 & 3) << 4));
  }
  const int dstw = wid * 1024;

  f32x4 accG[4][4], accU[4][4];
#pragma unroll
  for (int i = 0; i < 4; ++i)
#pragma unroll
    for (int j = 0; j < 4; ++j) {
      accG[i][j] = (f32x4){0.f, 0.f, 0.f, 0.f};
      accU[i][j] = (f32x4){0.f, 0.f, 0.f, 0.f};
    }

  const int NT = DH / 32;  // 64
  // prologue: stage tiles 0,1,2 (4 loads each)
#pragma unroll
  for (int t0 = 0; t0 < 3; ++t0) {
    int kk = t0 * 32;
    gload16(srcA[0] + kk, (ushort*)(sm + t0 * 16384 + dstw));
    gload16(srcA[1] + kk, (ushort*)(sm + t0 * 16384 + 8192 + dstw));
    gload16(srcBg   + kk, (ushort*)(sm + 65536 + t0 * 8192 + dstw));
    gload16(srcBu   + kk, (ushort*)(sm + 98304 + t0 * 8192 + dstw));
  }
  WAITV8();
  BARRIER();

  for (int t = 0; t < NT; ++t) {
    const int r = t & 3, w = (t + 3) & 3;
    char* Ab  = sm + r * 16384;
    char* Bgb = sm + 65536 + r * 8192;
    char* Bub = sm + 98304 + r * 8192;
    // ds reads (12 x b128)
    bf16x8 a[4], bg[4], bu[4];
#pragma unroll
    for (int i = 0; i < 4; ++i) a[i]  = *(const bf16x8*)(Ab + aoff[i]);
#pragma unroll
    for (int j = 0; j < 4; ++j) bg[j] = *(const bf16x8*)(Bgb + boff[j]);
#pragma unroll
    for (int j = 0; j < 4; ++j) bu[j] = *(const bf16x8*)(Bub + boff[j]);
    // stage tile t+3 into buffer w (disjoint from r and (t+1)&3, (t+2)&3)
    if (t + 3 < NT) {
      int kk = (t + 3) * 32;
      gload16(srcA[0] + kk, (ushort*)(sm + w * 16384 + dstw));
      gload16(srcA[1] + kk, (ushort*)(sm + w * 16384 + 8192 + dstw));
      gload16(srcBg   + kk, (ushort*)(sm + 65536 + w * 8192 + dstw));
      gload16(srcBu   + kk, (ushort*)(sm + 98304 + w * 8192 + dstw));
    }
    // 32 MFMA (compiler interleaves with read drain via fine lgkmcnt)
    SETPRIO(1);
#pragma unroll
    for (int j = 0; j < 4; ++j)
#pragma unroll
      for (int i = 0; i < 4; ++i)
        accG[i][j] = __builtin_amdgcn_mfma_f32_16x16x32_bf16(a[i], bg[j], accG[i][j], 0, 0, 0);
#pragma unroll
    for (int j = 0; j < 4; ++j)
#pragma unroll
      for (int i = 0; i < 4; ++i)
        accU[i][j] = __builtin_amdgcn_mfma_f32_16x16x32_bf16(a[i], bu[j], accU[i][j], 0, 0, 0);
    SETPRIO(0);
    if (t >= NT - 2) { WAITV0(); } else { WAITV8(); }
    BARRIER();
  }
  // epilogue: SwiGLU -> h (stride DFP)
  const size_t rowbase = (size_t)(e * CAP + mt * 256 + wr * 64);
#pragma unroll
  for (int j = 0; j < 4; ++j) {
    int col = n0 + wc * 64 + j * 16 + l15;
    if (col < DF) {
#pragma unroll
      for (int i = 0; i < 4; ++i)
#pragma unroll
        for (int r2 = 0; r2 < 4; ++r2) {
          size_t row = rowbase + i * 16 + l4 * 4 + r2;
          float gv = accG[i][j][r2], uv = accU[i][j][r2];
          h[row * DFP + col] = bf16bits(gv / (1.f + __expf(-gv)) * uv);
        }
    }
  }
}

// ======================================================================
// GEMM2 (256Mx128N, BK=64, TRIPLE-buffer, 8 waves 4Mx2N of 64x64):
//   y[token] = (H*Wd)*score
// ONE barrier per K-tile: region = {16 ds_read | 6 gload(t+2) | 32 MFMA}
// LDS ~146KB: A[3][32KB]@0, B[3][16KB]@96K, tokc@144K, scc@145K
// 128B rows: swizzle byte ^= ((row&7)<<4) (proven round-4 layout).
// vmcnt: 6 loads/tile, 2 tiles in flight -> WAITV6; V0 at t>=NT-2.
// ======================================================================
__global__ __launch_bounds__(512, 1) void gemm_down3(
    const ushort* __restrict__ h, const ushort* __restrict__ wdt,
    const int* __restrict__ tok_slot, const float* __restrict__ scores,
    float* __restrict__ y)
{
  __shared__ __align__(16) char sm[149504];
  int* tokc = (int*)(sm + 147456);
  float* scc = (float*)(sm + 148480);
  const int tid = threadIdx.x, lane = tid & 63, wid = tid >> 6;
  const int wr = wid >> 1, wc = wid & 1;
  const int l15 = lane & 15, l4 = lane >> 4;

  // XCD swizzle: 640 blocks = 8 XCDs x 80 (one expert: 5 mt x 16 nt)
  int wgid = (blockIdx.x & 7) * 80 + (blockIdx.x >> 3);
  const int e = wgid / 80;
  const int rem = wgid - e * 80;
  const int mt = rem / 16, nt = rem & 15;
  const int n0 = nt * 128;

  if (tid < 256) {
    int tk = tok_slot[e * CAP + mt * 256 + tid];
    tokc[tid] = tk;
    scc[tid] = (tk >= 0) ? scores[tk] : 0.f;
  }
  __syncthreads();

  const size_t hrow0 = (size_t)(e * CAP + mt * 256);
  const ushort* srcA[4]; const ushort* srcB[2];
#pragma unroll
  for (int c = 0; c < 4; ++c) {
    int o = c * 8192 + wid * 1024 + lane * 16;       // within 32KB A tile
    int os = o ^ (((o >> 7) & 7) << 4);
    int row = os >> 7, kb = os & 127;
    srcA[c] = h + (hrow0 + row) * DFP + (kb >> 1);
  }
#pragma unroll
  for (int c = 0; c < 2; ++c) {
    int o = c * 8192 + wid * 1024 + lane * 16;       // within 16KB B tile
    int os = o ^ (((o >> 7) & 7) << 4);
    int row = os >> 7, kb = os & 127;
    srcB[c] = wdt + ((size_t)e * DH + n0 + row) * DF + (kb >> 1);   // stride DF
  }
  int aoff0[4], aoff1[4], boff0[4], boff1[4];
#pragma unroll
  for (int i = 0; i < 4; ++i) {
    int row = wr * 64 + i * 16 + l15;
    int r4 = (row & 7) << 4;
    aoff0[i] = row * 128 + ((l4 * 16) ^ r4);
    aoff1[i] = row * 128 + ((l4 * 16 + 64) ^ r4);
  }
#pragma unroll
  for (int j = 0; j < 4; ++j) {
    int row = wc * 64 + j * 16 + l15;
    int r4 = (row & 7) << 4;
    boff0[j] = row * 128 + ((l4 * 16) ^ r4);
    boff1[j] = row * 128 + ((l4 * 16 + 64) ^ r4);
  }
  const int dstw = wid * 1024;

  f32x4 acc[4][4];
#pragma unroll
  for (int i = 0; i < 4; ++i)
#pragma unroll
    for (int j = 0; j < 4; ++j) acc[i][j] = (f32x4){0.f, 0.f, 0.f, 0.f};

  const int NT = DFP / 64;  // 22 (A pad cols zero; B tail killed by A zeros)
  // prologue: stage tiles 0,1 (6 loads each)
#pragma unroll
  for (int t0 = 0; t0 < 2; ++t0) {
    int kk = t0 * 64;
#pragma unroll
    for (int c = 0; c < 4; ++c)
      gload16(srcA[c] + kk, (ushort*)(sm + t0 * 32768 + c * 8192 + dstw));
#pragma unroll
    for (int c = 0; c < 2; ++c)
      gload16(srcB[c] + kk, (ushort*)(sm + 98304 + t0 * 16384 + c * 8192 + dstw));
  }
  WAITV6();
  BARRIER();

  int rrot = 0, wrot = 2;
  for (int t = 0; t < NT; ++t) {
    char* Ab = sm + rrot * 32768;
    char* Bb = sm + 98304 + rrot * 16384;
    // ds reads (16 x b128)
    bf16x8 a0[4], a1[4], b0[4], b1[4];
#pragma unroll
    for (int i = 0; i < 4; ++i) a0[i] = *(const bf16x8*)(Ab + aoff0[i]);
#pragma unroll
    for (int j = 0; j < 4; ++j) b0[j] = *(const bf16x8*)(Bb + boff0[j]);
#pragma unroll
    for (int i = 0; i < 4; ++i) a1[i] = *(const bf16x8*)(Ab + aoff1[i]);
#pragma unroll
    for (int j = 0; j < 4; ++j) b1[j] = *(const bf16x8*)(Bb + boff1[j]);
    // stage tile t+2 into buffer wrot (disjoint from rrot and (t+1)%3)
    if (t + 2 < NT) {
      int kk = (t + 2) * 64;
#pragma unroll
      for (int c = 0; c < 4; ++c)
        gload16(srcA[c] + kk, (ushort*)(sm + wrot * 32768 + c * 8192 + dstw));
#pragma unroll
      for (int c = 0; c < 2; ++c)
        gload16(srcB[c] + kk, (ushort*)(sm + 98304 + wrot * 16384 + c * 8192 + dstw));
    }
    // 32 MFMA
    SETPRIO(1);
#pragma unroll
    for (int j = 0; j < 4; ++j)
#pragma unroll
      for (int i = 0; i < 4; ++i)
        acc[i][j] = __builtin_amdgcn_mfma_f32_16x16x32_bf16(a0[i], b0[j], acc[i][j], 0, 0, 0);
#pragma unroll
    for (int j = 0; j < 4; ++j)
#pragma unroll
      for (int i = 0; i < 4; ++i)
        acc[i][j] = __builtin_amdgcn_mfma_f32_16x16x32_bf16(a1[i], b1[j], acc[i][j], 0, 0, 0);
    SETPRIO(0);
    if (t >= NT - 2) { WAITV0(); } else { WAITV6(); }
    BARRIER();
    rrot = (rrot == 2) ? 0 : rrot + 1;
    wrot = (wrot == 2) ? 0 : wrot + 1;
  }
  // epilogue: scatter * score
  int tkr[4][4]; float sr[4][4];
#pragma unroll
  for (int i = 0; i < 4; ++i)
#pragma unroll
    for (int r = 0; r < 4; ++r) {
      int rl = wr * 64 + i * 16 + l4 * 4 + r;
      tkr[i][r] = tokc[rl];
      sr[i][r]  = scc[rl];
    }
#pragma unroll
  for (int j = 0; j < 4; ++j) {
    int col = n0 + wc * 64 + j * 16 + l15;
#pragma unroll
    for (int i = 0; i < 4; ++i)
#pragma unroll
      for (int r = 0; r < 4; ++r)
        if (tkr[i][r] >= 0)
          y[(size_t)tkr[i][r] * DH + col] = acc[i][j][r] * sr[i][r];
  }
}

extern "C" void kernel_launch(void* const* d_in, const int* in_sizes, int n_in,
                              void* d_out, int out_size, void* d_ws, size_t ws_size,
                              hipStream_t stream) {
  const float* x   = (const float*)d_in[0];
  const int*   idx = (const int*)d_in[1];
  const float* sc  = (const float*)d_in[2];
  const float* wg  = (const float*)d_in[3];
  const float* wu  = (const float*)d_in[4];
  const float* wd  = (const float*)d_in[5];
  float* y = (float*)d_out;

  // ws layout (~152.6 MB; wdt reuses wgt region after gateup)
  const size_t OFF_KEEP = 40960;                       // tok_slot [0,40960)
  const size_t OFF_H    = 73728;                       // keep [40960,73728)
  const size_t SZ_H     = (size_t)NE * CAP * DFP * 2;  // 28,835,840
  const size_t OFF_XB   = OFF_H + SZ_H;                // 28,909,568
  const size_t SZ_XB    = (size_t)NTOK * DH * 2;       // 33,554,432
  const size_t OFF_WGT  = OFF_XB + SZ_XB;              // 62,464,000
  const size_t SZ_W     = (size_t)NE * DH * DF * 2;    // 45,088,768
  const size_t OFF_WUT  = OFF_WGT + SZ_W;              // 107,552,768

  int* tok_slot = (int*)d_ws;
  int* tok_keep = (int*)((char*)d_ws + OFF_KEEP);
  ushort* hbuf = (ushort*)((char*)d_ws + OFF_H);
  ushort* xb   = (ushort*)((char*)d_ws + OFF_XB);
  ushort* wgt  = (ushort*)((char*)d_ws + OFF_WGT);
  ushort* wut  = (ushort*)((char*)d_ws + OFF_WUT);
  ushort* wdt  = wgt;   // dead after gateup

  hipLaunchKernelGGL(routing_kernel, dim3(1), dim3(256), 0, stream, idx, tok_slot, tok_keep);
  hipLaunchKernelGGL(zero_dropped, dim3(NTOK), dim3(256), 0, stream, tok_keep, y);
  hipLaunchKernelGGL(convert_x, dim3(NTOK * DH / 2048), dim3(256), 0, stream, x, xb);
  hipLaunchKernelGGL(transpose_cvt, dim3((DF + 63) / 64, DH / 64, NE), dim3(256), 0, stream,
                     wg, wgt, DH, DF);
  hipLaunchKernelGGL(transpose_cvt, dim3((DF + 63) / 64, DH / 64, NE), dim3(256), 0, stream,
                     wu, wut, DH, DF);
  hipLaunchKernelGGL(pad_h, dim3(80), dim3(512), 0, stream, hbuf);
  hipLaunchKernelGGL(gemm_gateup3, dim3(440), dim3(512), 0, stream,
                     xb, wgt, wut, tok_slot, hbuf);
  hipLaunchKernelGGL(transpose_cvt, dim3(DH / 64, (DF + 63) / 64, NE), dim3(256), 0, stream,
                     wd, wdt, DF, DH);
  hipLaunchKernelGGL(gemm_down3, dim3(640), dim3(512), 0, stream,
                     hbuf, wdt, tok_slot, sc, y);
}